// Round 7
// baseline (594.657 us; speedup 1.0000x reference)
//
#include <hip/hip_runtime.h>
#include <math.h>

// Problem constants (from reference)
#define N_ELEMS 8000000
#define GL_F       0.1f
#define EL_F       -5.0f
#define IEXT_F     0.4f
#define CM_F       0.3f
#define INV_CM     (1.0f / 0.3f)
#define INV_DTS    2.0f               // 1/DTS, DTS=0.5
#define COEF       0.4f               // 0.5*(1 - DT/DTS)
#define INV_SQRT3  0.57735026918962576f   // 1/(SIGMA*SQ2) = 1/sqrt(3)
#define SQ2_F      1.41421356237309515f
#define SQ2PI_F    0.7978845608028654f

#define NBLOCKS 7813    // ceil(2,000,000 / 256)

typedef float v4f __attribute__((ext_vector_type(4)));

// limiter: reference where-chain is degenerate (idx1&idx2==False always)
__device__ __forceinline__ float limiter(float a, float b) {
    return fminf(0.5f * fabsf(a + b), 2.0f * fminf(fabsf(a), fabsf(b)));
}

// interior _update_z term (without the -src part), branch-free.
// j==1's wi_1=0 is handled by the caller faking z[-1]:=z[0] (limiter(x,0)==0).
__device__ __forceinline__ float upd_mid(float zm2, float zm1, float z0,
                                         float zp1) {
    float dm1 = z0 - zm1;
    float d0  = zp1 - z0;
    return -(dm1 + COEF * (limiter(d0, dm1) - limiter(dm1, zm1 - zm2))) * INV_DTS;
}

// erf via Abramowitz-Stegun 7.1.26 (|err| <= 1.5e-7), shares e2 = exp(-T^2)
__device__ __forceinline__ float erf_as(float x, float e2) {
    float ax = fabsf(x);
    float t  = __fdividef(1.0f, fmaf(0.3275911f, ax, 1.0f));
    float p  = t * fmaf(t, fmaf(t, fmaf(t, fmaf(t, 1.061405429f, -1.453152027f),
                                        1.421413741f), -0.284496736f), 0.254829592f);
    float e  = 1.0f - p * e2;
    return (x < 0.0f) ? -e : e;
}

// H * (1/tau_m): A*inv_tau + (-sqrt2*dTdt*SQ2PI)*e2/denom
// (tau_m in B cancels against /tau_m in H). __expf is base-e (R2 errata).
__device__ __forceinline__ float Hfun(float V0, float dVdt, float inv_tau) {
    float dv = fmaxf(-V0, -1.0f);          // VT = 0
    float T  = dv * INV_SQRT3;
    float p  = 0.0061f + T * (-1.12f + T * (-0.257f + T * (-0.072f + T * (-0.0117f))));
    float A  = __expf(p);
    float e2 = __expf(-T * T);
    float denom = 1.00000001f + erf_as(T, e2);
    float dTdt  = fminf(-dVdt * INV_SQRT3, 0.0f);
    float Bov   = -SQ2_F * dTdt * SQ2PI_F * __fdividef(e2, denom);  // B / tau_m
    return fmaxf(fmaf(A, inv_tau, Bov), 0.0f);
}

// Fused single-pass kernel (R6 net_main + last-block-done finale).
// 4 elements/thread (float4 loads), stencil halos via wave shuffles; lanes
// 0/63 do guarded global halo loads. Interior path is branch-free; boundary
// elements compute garbage and are patched by the last-finishing block.
// Cross-XCD protocol: partial published with agent-scope atomic store ->
// __threadfence (release) -> device-scope counter fetch_add; the winning
// block fences (acquire) and reads partials with agent-scope atomic loads.
__global__ __launch_bounds__(256) void net_all(
    const float* __restrict__ y, const float* __restrict__ gsyn,
    const float* __restrict__ Isyn_p, float* __restrict__ out,
    float* __restrict__ partials, unsigned* __restrict__ counter)
{
    const float* ro = y;
    const float* V  = y + N_ELEMS;

    int tid  = blockIdx.x * 256 + threadIdx.x;
    int j0   = tid * 4;
    int lane = threadIdx.x & 63;

    float gs      = gsyn[0];
    float Isyn    = Isyn_p[0];
    float inv_tau = (GL_F + gs) * INV_CM;                   // 1/tau_m
    float c1      = (GL_F * EL_F + IEXT_F + Isyn) * INV_CM; // dVdt = c1 - V/3
    float acc = 0.0f;

    if (j0 < N_ELEMS) {
        float4 r4 = *(const float4*)(ro + j0);
        float4 v4 = *(const float4*)(V + j0);

        // halos via cross-lane shuffle (adjacent lanes hold the neighbors)
        float rm2 = __shfl_up(r4.z, 1);
        float rm1 = __shfl_up(r4.w, 1);
        float rp1 = __shfl_down(r4.x, 1);
        float vm2 = __shfl_up(v4.z, 1);
        float vm1 = __shfl_up(v4.w, 1);
        float vp1 = __shfl_down(v4.x, 1);
        if (lane == 0) {
            // j0==0: fake z[-1]:=z[0] so j==1's wi_1 = limiter(.,0) = 0;
            // z[-2] only feeds the discarded j==0 output.
            rm2 = (j0 > 0) ? ro[j0 - 2] : r4.x;
            rm1 = (j0 > 0) ? ro[j0 - 1] : r4.x;
            vm2 = (j0 > 0) ? V[j0 - 2] : v4.x;
            vm1 = (j0 > 0) ? V[j0 - 1] : v4.x;
        }
        if (lane == 63) {
            rp1 = (j0 + 4 < N_ELEMS) ? ro[j0 + 4] : 0.0f;
            vp1 = (j0 + 4 < N_ELEMS) ? V[j0 + 4] : 0.0f;
        }

        float rz[7] = {rm2, rm1, r4.x, r4.y, r4.z, r4.w, rp1};
        float vz[7] = {vm2, vm1, v4.x, v4.y, v4.z, v4.w, vp1};
        float oro[4], ov[4];

        #pragma unroll
        for (int k = 0; k < 4; ++k) {
            float V0   = vz[2 + k];
            float dVdt = fmaf(-INV_CM * GL_F, V0, c1);
            float Hov  = Hfun(V0, dVdt, inv_tau);   // H/tau (includes /tau)
            float srcj = rz[2 + k] * Hov;
            acc += srcj;
            oro[k] = upd_mid(rz[k], rz[1 + k], rz[2 + k], rz[3 + k]) - srcj;
            ov[k]  = upd_mid(vz[k], vz[1 + k], vz[2 + k], vz[3 + k]) + dVdt;
        }

        v4f o1 = {oro[0], oro[1], oro[2], oro[3]};
        v4f o2 = {ov[0], ov[1], ov[2], ov[3]};
        __builtin_nontemporal_store(o1, (v4f*)(out + j0));
        __builtin_nontemporal_store(o2, (v4f*)(out + N_ELEMS + j0));
    }

    // block reduction (wave64 shuffle, then cross-wave via LDS)
    #pragma unroll
    for (int off = 32; off > 0; off >>= 1)
        acc += __shfl_down(acc, off);
    __shared__ float sred[4];
    if ((threadIdx.x & 63) == 0) sred[threadIdx.x >> 6] = acc;
    __syncthreads();

    // publish partial, then find out if we're the last block to finish
    __shared__ bool s_last;
    if (threadIdx.x == 0) {
        float bsum = sred[0] + sred[1] + sred[2] + sred[3];
        __hip_atomic_store(&partials[blockIdx.x], bsum, __ATOMIC_RELAXED,
                           __HIP_MEMORY_SCOPE_AGENT);
        __threadfence();                         // release: partial + outputs
        unsigned old = __hip_atomic_fetch_add(counter, 1u, __ATOMIC_ACQ_REL,
                                              __HIP_MEMORY_SCOPE_AGENT);
        s_last = (old == NBLOCKS - 1);
    }
    __syncthreads();
    if (!s_last) return;

    // ---- last block: reduce partials (same order as old net_fix0) ----
    __threadfence();                             // acquire
    float a = 0.0f;
    for (int i = threadIdx.x; i < NBLOCKS; i += 256)
        a += __hip_atomic_load(&partials[i], __ATOMIC_RELAXED,
                               __HIP_MEMORY_SCOPE_AGENT);
    __shared__ float sh[256];
    sh[threadIdx.x] = a;
    __syncthreads();
    for (int s = 128; s > 0; s >>= 1) {
        if (threadIdx.x < s) sh[threadIdx.x] += sh[threadIdx.x + s];
        __syncthreads();
    }
    if (threadIdx.x == 0) {
        float firing = sh[0];
        // patch boundary outputs
        out[0] = fmaf(-INV_DTS, y[0], firing);   // src[0] := -firing
        out[N_ELEMS] = 0.0f;                     // dV_dt[0]

        float rN1 = y[N_ELEMS - 1];
        float rN2 = y[N_ELEMS - 2];
        float rN3 = y[N_ELEMS - 3];
        float VN1 = y[2 * N_ELEMS - 1];
        float dVdtN = fmaf(-INV_CM * GL_F, VN1, c1);
        float srcN  = rN1 * Hfun(VN1, dVdtN, inv_tau);
        float wi    = limiter(rN1 - rN2, rN2 - rN3);
        out[N_ELEMS - 1]     = (rN2 + COEF * wi) * INV_DTS - srcN;
        out[2 * N_ELEMS - 1] = dVdtN;            // dV_dt[-1]
    }
}

extern "C" void kernel_launch(void* const* d_in, const int* in_sizes, int n_in,
                              void* d_out, int out_size, void* d_ws, size_t ws_size,
                              hipStream_t stream)
{
    // setup_inputs order: t, y, gsyn, Isyn
    const float* y    = (const float*)d_in[1];
    const float* gsyn = (const float*)d_in[2];
    const float* Isyn = (const float*)d_in[3];
    float* out = (float*)d_out;
    float* partials   = (float*)d_ws;                       // NBLOCKS floats
    unsigned* counter = (unsigned*)((char*)d_ws + 32768);   // past partials

    // graph-legal async memset node: zero the arrival counter every call
    hipMemsetAsync(counter, 0, sizeof(unsigned), stream);

    net_all<<<NBLOCKS, 256, 0, stream>>>(y, gsyn, Isyn, out, partials, counter);
}

// Round 8
// 123.927 us; speedup vs baseline: 4.7984x; 4.7984x over previous
//
#include <hip/hip_runtime.h>
#include <math.h>

// Problem constants (from reference)
#define N_ELEMS 8000000
#define GL_F       0.1f
#define EL_F       -5.0f
#define IEXT_F     0.4f
#define CM_F       0.3f
#define INV_CM     (1.0f / 0.3f)
#define INV_DTS    2.0f               // 1/DTS, DTS=0.5
#define COEF       0.4f               // 0.5*(1 - DT/DTS)
#define INV_SQRT3  0.57735026918962576f   // 1/(SIGMA*SQ2) = 1/sqrt(3)
#define SQ2_F      1.41421356237309515f
#define SQ2PI_F    0.7978845608028654f

#define ITER    4                      // chunks per thread
#define NB      1954                   // ceil(2,000,000 / (256*ITER))
#define STRIDE  (NB * 256 * 4)         // elements between a thread's chunks

typedef float v4f __attribute__((ext_vector_type(4)));

// limiter: reference where-chain is degenerate (idx1&idx2==False always)
__device__ __forceinline__ float limiter(float a, float b) {
    return fminf(0.5f * fabsf(a + b), 2.0f * fminf(fabsf(a), fabsf(b)));
}

// interior _update_z term (without the -src part), branch-free.
// j==1's wi_1=0 is handled by faking z[-1]:=z[0] (limiter(x,0)==0).
__device__ __forceinline__ float upd_mid(float zm2, float zm1, float z0,
                                         float zp1) {
    float dm1 = z0 - zm1;
    float d0  = zp1 - z0;
    return -(dm1 + COEF * (limiter(d0, dm1) - limiter(dm1, zm1 - zm2))) * INV_DTS;
}

// erf via Abramowitz-Stegun 7.1.26 (|err| <= 1.5e-7), shares e2 = exp(-T^2)
__device__ __forceinline__ float erf_as(float x, float e2) {
    float ax = fabsf(x);
    float t  = __fdividef(1.0f, fmaf(0.3275911f, ax, 1.0f));
    float p  = t * fmaf(t, fmaf(t, fmaf(t, fmaf(t, 1.061405429f, -1.453152027f),
                                        1.421413741f), -0.284496736f), 0.254829592f);
    float e  = 1.0f - p * e2;
    return (x < 0.0f) ? -e : e;
}

// H * (1/tau_m): A*inv_tau + (-sqrt2*dTdt*SQ2PI)*e2/denom
// (tau_m in B cancels against /tau_m in H). __expf is base-e (R2 errata).
__device__ __forceinline__ float Hfun(float V0, float dVdt, float inv_tau) {
    float dv = fmaxf(-V0, -1.0f);          // VT = 0
    float T  = dv * INV_SQRT3;
    float p  = 0.0061f + T * (-1.12f + T * (-0.257f + T * (-0.072f + T * (-0.0117f))));
    float A  = __expf(p);
    float e2 = __expf(-T * T);
    float denom = 1.00000001f + erf_as(T, e2);
    float dTdt  = fminf(-dVdt * INV_SQRT3, 0.0f);
    float Bov   = -SQ2_F * dTdt * SQ2PI_F * __fdividef(e2, denom);  // B / tau_m
    return fmaxf(fmaf(A, inv_tau, Bov), 0.0f);
}

// Software-pipelined grid-stride kernel: ITER chunks of 4 elements per thread,
// whole grid co-resident (1954 blocks = 7816 waves ~ 31/CU). Chunk c+1's
// global loads (float4 x2 + edge-lane halo scalars) are issued BEFORE chunk
// c's compute, hiding HBM latency under the ~350-instr compute phase.
// Validity is wave-uniform (2M threads = 31250 exact waves; 896-thread
// overshoot = 14 exact waves), so shuffles inside if(valid) are safe.
// Boundary outputs (j=0, j=N-1, dV ends) are garbage here; net_fix0 patches.
// NOTE (R7 errata): no __threadfence here — device-scope release on gfx950
// costs an L2 writeback; doing it per-block was a 4.5x regression.
__global__ __launch_bounds__(256) void net_main(
    const float* __restrict__ y, const float* __restrict__ gsyn,
    const float* __restrict__ Isyn_p, float* __restrict__ out,
    float* __restrict__ partials)
{
    const float* ro = y;
    const float* V  = y + N_ELEMS;

    int  lane = threadIdx.x & 63;
    int  j    = (blockIdx.x * 256 + threadIdx.x) * 4;   // chunk 0

    float gs      = gsyn[0];
    float Isyn    = Isyn_p[0];
    float inv_tau = (GL_F + gs) * INV_CM;                   // 1/tau_m
    float c1      = (GL_F * EL_F + IEXT_F + Isyn) * INV_CM; // dVdt = c1 - V/3
    float acc = 0.0f;

    // ---- prefetch chunk 0 ----
    bool valid = (j < N_ELEMS);
    v4f r4 = {0,0,0,0}, v4 = {0,0,0,0};
    float rh0=0, rh1=0, rh2=0, vh0=0, vh1=0, vh2=0;  // edge-lane halo scalars
    if (valid) {
        r4 = *(const v4f*)(ro + j);
        v4 = *(const v4f*)(V + j);
        if (lane == 0 && j > 0) {
            rh0 = ro[j - 2]; rh1 = ro[j - 1];
            vh0 = V[j - 2];  vh1 = V[j - 1];
        }
        if (lane == 63 && j + 4 < N_ELEMS) {
            rh2 = ro[j + 4]; vh2 = V[j + 4];
        }
    }

    #pragma unroll
    for (int c = 0; c < ITER; ++c) {
        // ---- prefetch chunk c+1 (issued before current compute) ----
        int  jn = j + STRIDE;
        bool validn = (c + 1 < ITER) && (jn < N_ELEMS);
        v4f rn = {0,0,0,0}, vn = {0,0,0,0};
        float rhn0=0, rhn1=0, rhn2=0, vhn0=0, vhn1=0, vhn2=0;
        if (validn) {
            rn = *(const v4f*)(ro + jn);
            vn = *(const v4f*)(V + jn);
            if (lane == 0) {                 // jn > 0 always (jn >= STRIDE)
                rhn0 = ro[jn - 2]; rhn1 = ro[jn - 1];
                vhn0 = V[jn - 2];  vhn1 = V[jn - 1];
            }
            if (lane == 63 && jn + 4 < N_ELEMS) {
                rhn2 = ro[jn + 4]; vhn2 = V[jn + 4];
            }
        }

        // ---- compute current chunk ----
        if (valid) {
            float rm2 = __shfl_up(r4.z, 1);
            float rm1 = __shfl_up(r4.w, 1);
            float rp1 = __shfl_down(r4.x, 1);
            float vm2 = __shfl_up(v4.z, 1);
            float vm1 = __shfl_up(v4.w, 1);
            float vp1 = __shfl_down(v4.x, 1);
            if (lane == 0) {
                // j==0 (block 0, chunk 0): fake z[-1]:=z[0] so j==1's wi_1=0;
                // z[-2] only feeds the discarded j==0 output.
                rm2 = (j > 0) ? rh0 : r4.x;
                rm1 = (j > 0) ? rh1 : r4.x;
                vm2 = (j > 0) ? vh0 : v4.x;
                vm1 = (j > 0) ? vh1 : v4.x;
            }
            if (lane == 63) {
                rp1 = (j + 4 < N_ELEMS) ? rh2 : 0.0f;
                vp1 = (j + 4 < N_ELEMS) ? vh2 : 0.0f;
            }

            float rz[7] = {rm2, rm1, r4.x, r4.y, r4.z, r4.w, rp1};
            float vz[7] = {vm2, vm1, v4.x, v4.y, v4.z, v4.w, vp1};
            float oro[4], ov[4];

            #pragma unroll
            for (int k = 0; k < 4; ++k) {
                float V0   = vz[2 + k];
                float dVdt = fmaf(-INV_CM * GL_F, V0, c1);
                float Hov  = Hfun(V0, dVdt, inv_tau);   // H/tau
                float srcj = rz[2 + k] * Hov;
                acc += srcj;
                oro[k] = upd_mid(rz[k], rz[1 + k], rz[2 + k], rz[3 + k]) - srcj;
                ov[k]  = upd_mid(vz[k], vz[1 + k], vz[2 + k], vz[3 + k]) + dVdt;
            }

            v4f o1 = {oro[0], oro[1], oro[2], oro[3]};
            v4f o2 = {ov[0], ov[1], ov[2], ov[3]};
            __builtin_nontemporal_store(o1, (v4f*)(out + j));
            __builtin_nontemporal_store(o2, (v4f*)(out + N_ELEMS + j));
        }

        // rotate pipeline registers
        j = jn; valid = validn;
        r4 = rn; v4 = vn;
        rh0 = rhn0; rh1 = rhn1; rh2 = rhn2;
        vh0 = vhn0; vh1 = vhn1; vh2 = vhn2;
    }

    // block reduction (wave64 shuffle, then cross-wave via LDS)
    #pragma unroll
    for (int off = 32; off > 0; off >>= 1)
        acc += __shfl_down(acc, off);
    __shared__ float sred[4];
    if ((threadIdx.x & 63) == 0) sred[threadIdx.x >> 6] = acc;
    __syncthreads();
    if (threadIdx.x == 0)
        partials[blockIdx.x] = sred[0] + sred[1] + sred[2] + sred[3];
}

// Reduce per-block partials -> firing; patch all boundary outputs:
//   out[0]      = -2*ro[0] + firing           (src[0] := -firing)
//   out[N-1]    = (ro[N-2] + coef*wi_last)*2 - src[N-1]
//   out[N]      = 0                            (dV_dt[0])
//   out[2N-1]   = dVdt[N-1]                    (dV_dt[-1])
__global__ __launch_bounds__(256) void net_fix0(
    const float* __restrict__ y, const float* __restrict__ gsyn,
    const float* __restrict__ Isyn_p, const float* __restrict__ partials,
    int nparts, float* __restrict__ out)
{
    __shared__ float sh[256];
    float a = 0.0f;
    for (int i = threadIdx.x; i < nparts; i += 256)
        a += partials[i];
    sh[threadIdx.x] = a;
    __syncthreads();
    for (int s = 128; s > 0; s >>= 1) {
        if (threadIdx.x < s) sh[threadIdx.x] += sh[threadIdx.x + s];
        __syncthreads();
    }
    if (threadIdx.x == 0) {
        float firing = sh[0];
        out[0] = fmaf(-INV_DTS, y[0], firing);
        out[N_ELEMS] = 0.0f;

        float gs      = gsyn[0];
        float Isyn    = Isyn_p[0];
        float inv_tau = (GL_F + gs) * INV_CM;
        float c1      = (GL_F * EL_F + IEXT_F + Isyn) * INV_CM;

        float rN1 = y[N_ELEMS - 1];
        float rN2 = y[N_ELEMS - 2];
        float rN3 = y[N_ELEMS - 3];
        float VN1 = y[2 * N_ELEMS - 1];
        float dVdtN = fmaf(-INV_CM * GL_F, VN1, c1);
        float srcN  = rN1 * Hfun(VN1, dVdtN, inv_tau);
        float wi    = limiter(rN1 - rN2, rN2 - rN3);
        out[N_ELEMS - 1]     = (rN2 + COEF * wi) * INV_DTS - srcN;
        out[2 * N_ELEMS - 1] = dVdtN;
    }
}

extern "C" void kernel_launch(void* const* d_in, const int* in_sizes, int n_in,
                              void* d_out, int out_size, void* d_ws, size_t ws_size,
                              hipStream_t stream)
{
    // setup_inputs order: t, y, gsyn, Isyn
    const float* y    = (const float*)d_in[1];
    const float* gsyn = (const float*)d_in[2];
    const float* Isyn = (const float*)d_in[3];
    float* out = (float*)d_out;
    float* partials = (float*)d_ws;   // NB floats, fully rewritten each call

    net_main<<<NB, 256, 0, stream>>>(y, gsyn, Isyn, out, partials);
    net_fix0<<<1, 256, 0, stream>>>(y, gsyn, Isyn, partials, NB, out);
}